// Round 12
// baseline (556.191 us; speedup 1.0000x reference)
//
#include <hip/hip_runtime.h>

#define NNODES 50000
#define NEDGES 1600000
#define NEG_SLOPE 0.2f

#define MT_ROWS 64
#define NMT 782       // ceil(50000/64)
#define GEMM_BLOCKS 768
#define SCAT_BLOCKS 1024
#define CAP 128       // padded CSR slots/node (max degree ~60 for Poisson(32))

typedef __attribute__((ext_vector_type(8))) short short8;
typedef __attribute__((ext_vector_type(4))) float f32x4;
typedef __attribute__((ext_vector_type(8))) _Float16 h16x8;
typedef __attribute__((ext_vector_type(8))) unsigned short us8;

static __device__ __forceinline__ unsigned short f2bf(float f) {
    unsigned u = __float_as_uint(f);
    unsigned r = u + 0x7FFFu + ((u >> 16) & 1u);   // RNE
    return (unsigned short)(r >> 16);
}
static __device__ __forceinline__ float bf2f(unsigned short h) {
    return __uint_as_float(((unsigned)h) << 16);
}

// ---------------- W prep: fp32 [k][n] -> transposed bf16 hi/lo [n][k] -------
__global__ __launch_bounds__(256) void k_wprep(const float* __restrict__ W0,
                                               const float* __restrict__ Wh,
                                               const float* __restrict__ Wout,
                                               unsigned short* __restrict__ wthi,
                                               unsigned short* __restrict__ wtlo) {
    int t = blockIdx.x * blockDim.x + threadIdx.x;   // 0..65535
    int l = t >> 14;
    int i = t & 16383;       // k*128+n
    int k = i >> 7, n = i & 127;
    const float* src = (l == 0) ? W0 : (l == 3) ? Wout : (Wh + (size_t)(l - 1) * 16384);
    float v = src[i];
    unsigned short h = f2bf(v);
    wthi[(size_t)l * 16384 + n * 128 + k] = h;
    wtlo[(size_t)l * 16384 + n * 128 + k] = f2bf(v - bf2f(h));
}

// ---------------- MFMA GEMM + attention epilogue (+ fused padded-CSR build) -
// C = X*W via split-bf16: Xh*Wh + Xh*Wl + Xl*Wh (err ~2^-17 rel).
// Layer 0: blocks >= GEMM_BLOCKS run the ONE-PASS padded-CSR build
// (atomicAdd rank + direct store into csr_pad[d*CAP+p]; no scan/scatter
// kernels needed). The atomic wall hides the layer-0 GEMM.
// Epilogue: acc -> LDS (fp16) -> coalesced us8 stores (fixes the 4x
// partial-line write amplification seen as WRITE_SIZE 69MB vs 20MB ideal).
__global__ __launch_bounds__(256, 3) void k_gemm_mfma(
        const float* __restrict__ X,
        const unsigned short* __restrict__ Ahi, const unsigned short* __restrict__ Alo,
        const unsigned short* __restrict__ Wthi, const unsigned short* __restrict__ Wtlo,
        const float* __restrict__ a_src, const float* __restrict__ a_dst,
        unsigned short* __restrict__ Hh,
        float* __restrict__ e_src, float* __restrict__ e_dst, int use_x,
        const int* __restrict__ ei, int* __restrict__ count, int* __restrict__ csr_pad)
{
    __shared__ __align__(16) short sAhi[MT_ROWS * 128];   // 16 KB (reused for H out)
    __shared__ __align__(16) short sAlo[MT_ROWS * 128];   // 16 KB
    __shared__ float eS[4][MT_ROWS];
    __shared__ float eD[4][MT_ROWS];

    if (blockIdx.x >= GEMM_BLOCKS) {
        // ---- one-pass padded-CSR build ----
        int gid = (blockIdx.x - GEMM_BLOCKS) * 256 + threadIdx.x;  // 0..262143
        #pragma unroll
        for (int k = 0; k < 7; k++) {
            int e = gid + k * (SCAT_BLOCKS * 256);
            if (e < NEDGES) {
                int s = ei[e];
                int d = ei[NEDGES + e];
                int p = atomicAdd(&count[d], 1);
                if (p < CAP)
                    __builtin_nontemporal_store(s, &csr_pad[(d << 7) + p]);
            }
        }
        return;
    }

    const int tid  = threadIdx.x;
    const int lane = tid & 63;
    const int w    = tid >> 6;
    const int l15  = lane & 15;
    const int quad = lane >> 4;

    short8 Bh[2][4], Bl[2][4];
    #pragma unroll
    for (int nt = 0; nt < 2; nt++) {
        int n = w * 32 + nt * 16 + l15;
        #pragma unroll
        for (int ks = 0; ks < 4; ks++) {
            Bh[nt][ks] = *(const short8*)(Wthi + (size_t)n * 128 + ks * 32 + quad * 8);
            Bl[nt][ks] = *(const short8*)(Wtlo + (size_t)n * 128 + ks * 32 + quad * 8);
        }
    }
    float as0 = a_src[w * 32 + l15],      ad0 = a_dst[w * 32 + l15];
    float as1 = a_src[w * 32 + 16 + l15], ad1 = a_dst[w * 32 + 16 + l15];

    for (int mt0 = blockIdx.x; mt0 < NMT; mt0 += GEMM_BLOCKS) {
        const int row0 = mt0 * MT_ROWS;

        for (int i = tid; i < MT_ROWS * 16; i += 256) {
            int m  = i >> 4;
            int kc = i & 15;
            int g  = row0 + m; if (g > NNODES - 1) g = NNODES - 1;
            int cp = kc ^ (m & 15);
            short8 vh, vl;
            if (use_x) {
                float4 xa = *(const float4*)(X + (size_t)g * 128 + kc * 8);
                float4 xb = *(const float4*)(X + (size_t)g * 128 + kc * 8 + 4);
                float xs[8] = {xa.x, xa.y, xa.z, xa.w, xb.x, xb.y, xb.z, xb.w};
                #pragma unroll
                for (int q = 0; q < 8; q++) {
                    unsigned short h = f2bf(xs[q]);
                    vh[q] = (short)h;
                    vl[q] = (short)f2bf(xs[q] - bf2f(h));
                }
            } else {
                vh = *(const short8*)(Ahi + (size_t)g * 128 + kc * 8);
                vl = *(const short8*)(Alo + (size_t)g * 128 + kc * 8);
            }
            *(short8*)&sAhi[m * 128 + cp * 8] = vh;
            *(short8*)&sAlo[m * 128 + cp * 8] = vl;
        }
        __syncthreads();

        f32x4 zero = {0.f, 0.f, 0.f, 0.f};
        f32x4 acc[4][2];
        #pragma unroll
        for (int mt = 0; mt < 4; mt++) { acc[mt][0] = zero; acc[mt][1] = zero; }
        #pragma unroll
        for (int mt = 0; mt < 4; mt++) {
            int m = mt * 16 + l15;
            #pragma unroll
            for (int ks = 0; ks < 4; ks++) {
                int kc = ks * 4 + quad;
                int cp = kc ^ l15;
                short8 ah = *(const short8*)&sAhi[m * 128 + cp * 8];
                short8 al = *(const short8*)&sAlo[m * 128 + cp * 8];
                #pragma unroll
                for (int nt = 0; nt < 2; nt++) {
                    acc[mt][nt] = __builtin_amdgcn_mfma_f32_16x16x32_bf16(ah, Bh[nt][ks], acc[mt][nt], 0, 0, 0);
                    acc[mt][nt] = __builtin_amdgcn_mfma_f32_16x16x32_bf16(al, Bh[nt][ks], acc[mt][nt], 0, 0, 0);
                    acc[mt][nt] = __builtin_amdgcn_mfma_f32_16x16x32_bf16(ah, Bl[nt][ks], acc[mt][nt], 0, 0, 0);
                }
            }
        }
        __syncthreads();   // all MFMA LDS reads done; sAhi can be reused

        // ---- epilogue: attention dots + fp16 H into LDS (coalesced store) ----
        _Float16* sH = (_Float16*)sAhi;
        #pragma unroll
        for (int mt = 0; mt < 4; mt++) {
            #pragma unroll
            for (int r = 0; r < 4; r++) {
                int m = mt * 16 + quad * 4 + r;
                float v0 = acc[mt][0][r], v1 = acc[mt][1][r];
                sH[m * 128 + w * 32 + l15]      = (_Float16)v0;
                sH[m * 128 + w * 32 + 16 + l15] = (_Float16)v1;
                float ps = v0 * as0 + v1 * as1;
                float pd = v0 * ad0 + v1 * ad1;
                ps += __shfl_xor(ps, 1); ps += __shfl_xor(ps, 2);
                ps += __shfl_xor(ps, 4); ps += __shfl_xor(ps, 8);
                pd += __shfl_xor(pd, 1); pd += __shfl_xor(pd, 2);
                pd += __shfl_xor(pd, 4); pd += __shfl_xor(pd, 8);
                if (l15 == 0) { eS[w][m] = ps; eD[w][m] = pd; }
            }
        }
        __syncthreads();
        #pragma unroll
        for (int i = 0; i < 4; i++) {
            int idx = i * 256 + tid;          // 0..1023
            int m   = idx >> 4;               // row 0..63
            int c8  = (idx & 15) * 8;         // col chunk
            int g   = row0 + m;
            if (g < NNODES)
                *(us8*)(Hh + (size_t)g * 128 + c8) = *(const us8*)(sH + m * 128 + c8);
        }
        if (tid < MT_ROWS * 2) {
            int m = tid >> 1, head = tid & 1;
            int g = row0 + m;
            if (g < NNODES) {
                e_src[g * 2 + head] = eS[head * 2][m] + eS[head * 2 + 1][m];
                e_dst[g * 2 + head] = eD[head * 2][m] + eD[head * 2 + 1][m];
            }
        }
        __syncthreads();
    }
}

// ---------------- aggregation: padded CSR, 16B/lane gathers -----------------
// lane: qt = lane>>4 (edge quarter), cl = lane&15 (channels cl*8..+7),
// head = cl>>3. Self-loop handled analytically (p_self * h[d], coalesced) —
// not stored in csr_pad. Merge quarters via shfl_xor(16,32).
template <int FINAL>
__device__ __forceinline__ void agg_body(const _Float16* __restrict__ Hh,
                                         const float* __restrict__ e_src,
                                         const float* __restrict__ e_dst,
                                         const int* __restrict__ count,
                                         const int* __restrict__ csr_pad,
                                         const float* __restrict__ bias,
                                         float* __restrict__ outf,
                                         unsigned short* __restrict__ ohi,
                                         unsigned short* __restrict__ olo) {
    int lane = threadIdx.x & 63;
    int wv   = threadIdx.x >> 6;
    int d    = blockIdx.x * 4 + wv;
    if (d >= NNODES) return;
    int qt   = lane >> 4;
    int cl   = lane & 15;
    int head = cl >> 3;
    int c0   = cl * 8;
    float ed = e_dst[d * 2 + head];
    int cnt = count[d]; if (cnt > CAP) cnt = CAP;
    const int* base = csr_pad + ((size_t)d << 7);
    // self-edge (only quarter 0 contributes; merged via shuffles below)
    float ts = e_src[d * 2 + head] + ed;
    ts = ts > 0.f ? ts : NEG_SLOPE * ts;
    float pself = (qt == 0) ? __expf(ts) : 0.f;
    h16x8 hs = *(const h16x8*)(Hh + (size_t)d * 128 + c0);
    float acc[8];
    #pragma unroll
    for (int c = 0; c < 8; c++) acc[c] = pself * (float)hs[c];
    float ssum = pself;
    int j = 0;
    for (; j + 16 <= cnt; j += 16) {
        int s0 = base[j + qt],      s1 = base[j + 4 + qt];
        int s2 = base[j + 8 + qt],  s3 = base[j + 12 + qt];
        h16x8 h0 = *(const h16x8*)(Hh + (size_t)s0 * 128 + c0);
        h16x8 h1 = *(const h16x8*)(Hh + (size_t)s1 * 128 + c0);
        h16x8 h2 = *(const h16x8*)(Hh + (size_t)s2 * 128 + c0);
        h16x8 h3 = *(const h16x8*)(Hh + (size_t)s3 * 128 + c0);
        float t0 = e_src[s0 * 2 + head] + ed, t1 = e_src[s1 * 2 + head] + ed;
        float t2 = e_src[s2 * 2 + head] + ed, t3 = e_src[s3 * 2 + head] + ed;
        t0 = t0 > 0.f ? t0 : NEG_SLOPE * t0;  t1 = t1 > 0.f ? t1 : NEG_SLOPE * t1;
        t2 = t2 > 0.f ? t2 : NEG_SLOPE * t2;  t3 = t3 > 0.f ? t3 : NEG_SLOPE * t3;
        float p0 = __expf(t0), p1 = __expf(t1), p2 = __expf(t2), p3 = __expf(t3);
        #pragma unroll
        for (int c = 0; c < 8; c++)
            acc[c] += p0 * (float)h0[c] + p1 * (float)h1[c]
                    + p2 * (float)h2[c] + p3 * (float)h3[c];
        ssum += p0 + p1 + p2 + p3;
    }
    for (; j < cnt; j += 4) {
        int idx = j + qt;
        bool valid = idx < cnt;
        int s = base[valid ? idx : cnt - 1];
        float t = e_src[s * 2 + head] + ed;
        t = t > 0.f ? t : NEG_SLOPE * t;
        float p = valid ? __expf(t) : 0.f;
        h16x8 hq = *(const h16x8*)(Hh + (size_t)s * 128 + c0);
        #pragma unroll
        for (int c = 0; c < 8; c++) acc[c] += p * (float)hq[c];
        ssum += p;
    }
    #pragma unroll
    for (int c = 0; c < 8; c++) {
        acc[c] += __shfl_xor(acc[c], 16);
        acc[c] += __shfl_xor(acc[c], 32);
    }
    ssum += __shfl_xor(ssum, 16);
    ssum += __shfl_xor(ssum, 32);
    if (qt == 0) {
        float inv = 1.0f / ssum;
        f32x4 b0 = *(const f32x4*)(bias + c0);
        f32x4 b1 = *(const f32x4*)(bias + c0 + 4);
        float o[8];
        #pragma unroll
        for (int c = 0; c < 8; c++) {
            float bv = (c < 4) ? b0[c] : b1[c - 4];
            o[c] = acc[c] * inv + bv;
        }
        if (FINAL) {
            f32x4 w0 = {o[0], o[1], o[2], o[3]};
            f32x4 w1 = {o[4], o[5], o[6], o[7]};
            *(f32x4*)(outf + (size_t)d * 128 + c0)     = w0;
            *(f32x4*)(outf + (size_t)d * 128 + c0 + 4) = w1;
        } else {
            us8 vh, vl;
            #pragma unroll
            for (int c = 0; c < 8; c++) {
                float oc = fmaxf(o[c], 0.f);
                unsigned short hbits = f2bf(oc);
                vh[c] = hbits;
                vl[c] = f2bf(oc - bf2f(hbits));
            }
            *(us8*)&ohi[(size_t)d * 128 + c0] = vh;
            *(us8*)&olo[(size_t)d * 128 + c0] = vl;
        }
    }
}

__global__ __launch_bounds__(256) void k_aggregate_h(const unsigned short* __restrict__ Hh,
                                                     const float* __restrict__ e_src,
                                                     const float* __restrict__ e_dst,
                                                     const int* __restrict__ count,
                                                     const int* __restrict__ csr_pad,
                                                     const float* __restrict__ bias,
                                                     unsigned short* __restrict__ ohi,
                                                     unsigned short* __restrict__ olo) {
    agg_body<0>((const _Float16*)Hh, e_src, e_dst, count, csr_pad, bias,
                nullptr, ohi, olo);
}

__global__ __launch_bounds__(256) void k_aggregate_f(const unsigned short* __restrict__ Hh,
                                                     const float* __restrict__ e_src,
                                                     const float* __restrict__ e_dst,
                                                     const int* __restrict__ count,
                                                     const int* __restrict__ csr_pad,
                                                     const float* __restrict__ bias,
                                                     float* __restrict__ outf) {
    agg_body<1>((const _Float16*)Hh, e_src, e_dst, count, csr_pad, bias,
                outf, nullptr, nullptr);
}

// ---------------- host ----------------

extern "C" void kernel_launch(void* const* d_in, const int* in_sizes, int n_in,
                              void* d_out, int out_size, void* d_ws, size_t ws_size,
                              hipStream_t stream) {
    const float* x  = (const float*)d_in[0];
    const int*   ei = (const int*)d_in[1];   // int32 (harness converts int64)

    char* ws = (char*)d_ws;
    size_t off = 0;
    auto alloc = [&](size_t bytes) {
        void* p = ws + off;
        off = (off + bytes + 255) & ~(size_t)255;
        return p;
    };
    int*            count   = (int*)alloc((size_t)NNODES * 4);
    int*            csr_pad = (int*)alloc((size_t)NNODES * CAP * 4);        // 25.6 MB
    unsigned short* hh      = (unsigned short*)alloc((size_t)NNODES * 128 * 2);
    unsigned short* wthi    = (unsigned short*)alloc((size_t)4 * 16384 * 2);
    unsigned short* wtlo    = (unsigned short*)alloc((size_t)4 * 16384 * 2);
    float*          es      = (float*)alloc((size_t)NNODES * 2 * 4);
    float*          edv     = (float*)alloc((size_t)NNODES * 2 * 4);
    (void)ws_size; (void)in_sizes; (void)n_in; (void)out_size;

    unsigned short* hi = (unsigned short*)d_out;     // act bf16 hi plane
    unsigned short* lo = hi + (size_t)NNODES * 128;  // act bf16 lo plane

    const float* W0   = (const float*)d_in[2];
    const float* W_h  = (const float*)d_in[6];
    const float* Wout = (const float*)d_in[10];

    const float* ash = (const float*)d_in[7];
    const float* adh = (const float*)d_in[8];
    const float* bh  = (const float*)d_in[9];

    struct Layer { const float *as, *ad, *b; };
    Layer L[4] = {
        { (const float*)d_in[3],  (const float*)d_in[4],  (const float*)d_in[5]  },
        { ash,        adh,        bh        },
        { ash + 128,  adh + 128,  bh + 128  },
        { (const float*)d_in[11], (const float*)d_in[12], (const float*)d_in[13] },
    };

    hipMemsetAsync(count, 0, (size_t)NNODES * 4, stream);
    k_wprep<<<256, 256, 0, stream>>>(W0, W_h, Wout, wthi, wtlo);

    const int agg_blocks = (NNODES + 3) / 4;
    for (int l = 0; l < 4; l++) {
        // layer 0: +SCAT_BLOCKS fused CSR-build blocks (atomic wall hides GEMM)
        int grid = (l == 0) ? GEMM_BLOCKS + SCAT_BLOCKS : GEMM_BLOCKS;
        k_gemm_mfma<<<grid, 256, 0, stream>>>(
            x, hi, lo, wthi + (size_t)l * 16384, wtlo + (size_t)l * 16384,
            L[l].as, L[l].ad, hh, es, edv, l == 0 ? 1 : 0, ei, count, csr_pad);
        if (l < 3) {
            k_aggregate_h<<<agg_blocks, 256, 0, stream>>>(hh, es, edv, count, csr_pad,
                                                          L[l].b, hi, lo);
        } else {
            k_aggregate_f<<<agg_blocks, 256, 0, stream>>>(hh, es, edv, count, csr_pad,
                                                          L[l].b, (float*)d_out);
        }
    }
}

// Round 13
// 542.216 us; speedup vs baseline: 1.0258x; 1.0258x over previous
//
#include <hip/hip_runtime.h>

#define NNODES 50000
#define NEDGES 1600000
#define NEG_SLOPE 0.2f

#define SCAN_NB 256
#define SCAN_CH 196   // ceil(50000/256)

#define MT_ROWS 64
#define NMT 782       // ceil(50000/64)
#define GEMM_BLOCKS 768
#define COUNT_BLOCKS 256

typedef __attribute__((ext_vector_type(8))) short short8;
typedef __attribute__((ext_vector_type(4))) float f32x4;
typedef __attribute__((ext_vector_type(8))) _Float16 h16x8;
typedef __attribute__((ext_vector_type(8))) unsigned short us8;

static __device__ __forceinline__ unsigned short f2bf(float f) {
    unsigned u = __float_as_uint(f);
    unsigned r = u + 0x7FFFu + ((u >> 16) & 1u);   // RNE
    return (unsigned short)(r >> 16);
}
static __device__ __forceinline__ float bf2f(unsigned short h) {
    return __uint_as_float(((unsigned)h) << 16);
}
static __device__ __forceinline__ unsigned short f2h(float f) {
    union { _Float16 x; unsigned short u; } c;
    c.x = (_Float16)f;
    return c.u;
}

// ---------------- CSR build (edge_index arrives as int32) ----------------
// k_count is FUSED into the layer-0 GEMM dispatch (independent work, disjoint
// resources: atomic path vs MFMA pipe) — see k_gemm_mfma.

__global__ __launch_bounds__(256) void k_bsum(const int* __restrict__ count,
                                              int* __restrict__ bsum) {
    __shared__ int red[4];
    int t = threadIdx.x, b = blockIdx.x;
    int idx = b * SCAN_CH + t;
    int v = (t < SCAN_CH && idx < NNODES) ? count[idx] + 1 : 0;   // +1 self loop
    #pragma unroll
    for (int m = 1; m <= 32; m <<= 1) v += __shfl_xor(v, m);
    if ((t & 63) == 0) red[t >> 6] = v;
    __syncthreads();
    if (t == 0) bsum[b] = red[0] + red[1] + red[2] + red[3];
}

__global__ __launch_bounds__(256) void k_bscan(const int* __restrict__ bsum,
                                               int* __restrict__ boff,
                                               int* __restrict__ row_ptr) {
    __shared__ int s[256];
    int t = threadIdx.x;
    int v = bsum[t];
    s[t] = v;
    __syncthreads();
    for (int off = 1; off < 256; off <<= 1) {
        int u = (t >= off) ? s[t - off] : 0;
        __syncthreads();
        s[t] += u;
        __syncthreads();
    }
    boff[t] = s[t] - v;
    if (t == 255) row_ptr[NNODES] = s[255];
}

__global__ __launch_bounds__(256) void k_rowptr(const int* __restrict__ count,
                                                const int* __restrict__ boff,
                                                int* __restrict__ row_ptr,
                                                int* __restrict__ csr_src) {
    __shared__ int s[256];
    int t = threadIdx.x, b = blockIdx.x;
    int idx = b * SCAN_CH + t;
    bool valid = (t < SCAN_CH && idx < NNODES);
    int v = valid ? count[idx] + 1 : 0;
    s[t] = v;
    __syncthreads();
    for (int off = 1; off < 256; off <<= 1) {
        int u = (t >= off) ? s[t - off] : 0;
        __syncthreads();
        s[t] += u;
        __syncthreads();
    }
    if (valid) {
        int run = boff[b] + s[t] - v;
        row_ptr[idx] = run;
        csr_src[run] = idx;                  // self-loop slot 0
    }
}

__global__ void k_scatter(const int* __restrict__ ei, const int* __restrict__ row_ptr,
                          const int* __restrict__ pos, int* __restrict__ csr_src) {
    int t = blockIdx.x * blockDim.x + threadIdx.x;
    int stride = gridDim.x * blockDim.x;
    #pragma unroll
    for (int i = 0; i < 4; i++) {
        int e = t + i * stride;
        if (e < NEDGES) {
            int s = ei[e];
            int d = ei[NEDGES + e];
            __builtin_nontemporal_store(s, &csr_src[row_ptr[d] + 1 + pos[e]]);
        }
    }
}

// ---------------- W prep: fp32 [k][n] -> transposed bf16 hi/lo [n][k] -------
__global__ __launch_bounds__(256) void k_wprep(const float* __restrict__ W0,
                                               const float* __restrict__ Wh,
                                               const float* __restrict__ Wout,
                                               unsigned short* __restrict__ wthi,
                                               unsigned short* __restrict__ wtlo) {
    int t = blockIdx.x * blockDim.x + threadIdx.x;   // 0..65535
    int l = t >> 14;
    int i = t & 16383;       // k*128+n
    int k = i >> 7, n = i & 127;
    const float* src = (l == 0) ? W0 : (l == 3) ? Wout : (Wh + (size_t)(l - 1) * 16384);
    float v = src[i];
    unsigned short h = f2bf(v);
    wthi[(size_t)l * 16384 + n * 128 + k] = h;
    wtlo[(size_t)l * 16384 + n * 128 + k] = f2bf(v - bf2f(h));
}

// ---------------- MFMA GEMM + attention epilogue (+ fused edge-count) -------
// C = X*W via split-bf16: Xh*Wh + Xh*Wl + Xl*Wh (err ~2^-17 rel).
// Blocks >= GEMM_BLOCKS run the CSR count pass (layer 0 only).
// Hh store: in-wave shuffle-pack to dwords -> each quad emits one contiguous
// 64B-aligned sector per row (fixes partial-line write amplification;
// NO LDS roundtrip -> no bank conflicts, cf. R12 failure).
__global__ __launch_bounds__(256, 3) void k_gemm_mfma(
        const float* __restrict__ X,
        const unsigned short* __restrict__ Ahi, const unsigned short* __restrict__ Alo,
        const unsigned short* __restrict__ Wthi, const unsigned short* __restrict__ Wtlo,
        const float* __restrict__ a_src, const float* __restrict__ a_dst,
        unsigned short* __restrict__ Hh,
        float* __restrict__ e_src, float* __restrict__ e_dst, int use_x,
        const int* __restrict__ ei, int* __restrict__ count, int* __restrict__ pos)
{
    __shared__ __align__(16) short sAhi[MT_ROWS * 128];   // 16 KB
    __shared__ __align__(16) short sAlo[MT_ROWS * 128];   // 16 KB
    __shared__ float eS[4][MT_ROWS];
    __shared__ float eD[4][MT_ROWS];

    if (blockIdx.x >= GEMM_BLOCKS) {
        // ---- fused CSR count path ----
        int t = (blockIdx.x - GEMM_BLOCKS) * 256 + threadIdx.x;   // 0..65535
        for (int base = t; base < NEDGES; base += 8 * 65536) {
            #pragma unroll
            for (int i = 0; i < 8; i++) {
                int e = base + i * 65536;
                if (e < NEDGES) pos[e] = atomicAdd(&count[ei[NEDGES + e]], 1);
            }
        }
        return;
    }

    const int tid  = threadIdx.x;
    const int lane = tid & 63;
    const int w    = tid >> 6;
    const int l15  = lane & 15;
    const int quad = lane >> 4;

    short8 Bh[2][4], Bl[2][4];
    #pragma unroll
    for (int nt = 0; nt < 2; nt++) {
        int n = w * 32 + nt * 16 + l15;
        #pragma unroll
        for (int ks = 0; ks < 4; ks++) {
            Bh[nt][ks] = *(const short8*)(Wthi + (size_t)n * 128 + ks * 32 + quad * 8);
            Bl[nt][ks] = *(const short8*)(Wtlo + (size_t)n * 128 + ks * 32 + quad * 8);
        }
    }
    float as0 = a_src[w * 32 + l15],      ad0 = a_dst[w * 32 + l15];
    float as1 = a_src[w * 32 + 16 + l15], ad1 = a_dst[w * 32 + 16 + l15];

    for (int mt0 = blockIdx.x; mt0 < NMT; mt0 += GEMM_BLOCKS) {
        const int row0 = mt0 * MT_ROWS;

        for (int i = tid; i < MT_ROWS * 16; i += 256) {
            int m  = i >> 4;
            int kc = i & 15;
            int g  = row0 + m; if (g > NNODES - 1) g = NNODES - 1;
            int cp = kc ^ (m & 15);
            short8 vh, vl;
            if (use_x) {
                float4 xa = *(const float4*)(X + (size_t)g * 128 + kc * 8);
                float4 xb = *(const float4*)(X + (size_t)g * 128 + kc * 8 + 4);
                float xs[8] = {xa.x, xa.y, xa.z, xa.w, xb.x, xb.y, xb.z, xb.w};
                #pragma unroll
                for (int q = 0; q < 8; q++) {
                    unsigned short h = f2bf(xs[q]);
                    vh[q] = (short)h;
                    vl[q] = (short)f2bf(xs[q] - bf2f(h));
                }
            } else {
                vh = *(const short8*)(Ahi + (size_t)g * 128 + kc * 8);
                vl = *(const short8*)(Alo + (size_t)g * 128 + kc * 8);
            }
            *(short8*)&sAhi[m * 128 + cp * 8] = vh;
            *(short8*)&sAlo[m * 128 + cp * 8] = vl;
        }
        __syncthreads();

        f32x4 zero = {0.f, 0.f, 0.f, 0.f};
        f32x4 acc[4][2];
        #pragma unroll
        for (int mt = 0; mt < 4; mt++) { acc[mt][0] = zero; acc[mt][1] = zero; }
        #pragma unroll
        for (int mt = 0; mt < 4; mt++) {
            int m = mt * 16 + l15;
            #pragma unroll
            for (int ks = 0; ks < 4; ks++) {
                int kc = ks * 4 + quad;
                int cp = kc ^ l15;
                short8 ah = *(const short8*)&sAhi[m * 128 + cp * 8];
                short8 al = *(const short8*)&sAlo[m * 128 + cp * 8];
                #pragma unroll
                for (int nt = 0; nt < 2; nt++) {
                    acc[mt][nt] = __builtin_amdgcn_mfma_f32_16x16x32_bf16(ah, Bh[nt][ks], acc[mt][nt], 0, 0, 0);
                    acc[mt][nt] = __builtin_amdgcn_mfma_f32_16x16x32_bf16(al, Bh[nt][ks], acc[mt][nt], 0, 0, 0);
                    acc[mt][nt] = __builtin_amdgcn_mfma_f32_16x16x32_bf16(ah, Bl[nt][ks], acc[mt][nt], 0, 0, 0);
                }
            }
        }

        #pragma unroll
        for (int mt = 0; mt < 4; mt++) {
            #pragma unroll
            for (int r = 0; r < 4; r++) {
                int m = mt * 16 + quad * 4 + r;   // the row this lane's quad owns
                int g = row0 + m;
                float v0 = acc[mt][0][r], v1 = acc[mt][1][r];
                // ---- packed 4B store: lane l15 takes cols 2*l15, 2*l15+1 ----
                int srcl = quad * 16 + ((2 * l15) & 15);
                float x0a = __shfl(v0, srcl), x0b = __shfl(v0, srcl + 1);
                float x1a = __shfl(v1, srcl), x1b = __shfl(v1, srcl + 1);
                float plo = (l15 < 8) ? x0a : x1a;
                float phi = (l15 < 8) ? x0b : x1b;
                unsigned pk = (unsigned)f2h(plo) | ((unsigned)f2h(phi) << 16);
                if (g < NNODES)
                    *(unsigned*)(Hh + (size_t)g * 128 + w * 32 + 2 * l15) = pk;
                // ---- attention dots (from unpacked fp32 values) ----
                float ps = v0 * as0 + v1 * as1;
                float pd = v0 * ad0 + v1 * ad1;
                ps += __shfl_xor(ps, 1); ps += __shfl_xor(ps, 2);
                ps += __shfl_xor(ps, 4); ps += __shfl_xor(ps, 8);
                pd += __shfl_xor(pd, 1); pd += __shfl_xor(pd, 2);
                pd += __shfl_xor(pd, 4); pd += __shfl_xor(pd, 8);
                if (l15 == 0) { eS[w][m] = ps; eD[w][m] = pd; }
            }
        }
        __syncthreads();
        if (tid < MT_ROWS * 2) {
            int m = tid >> 1, head = tid & 1;
            int g = row0 + m;
            if (g < NNODES) {
                e_src[g * 2 + head] = eS[head * 2][m] + eS[head * 2 + 1][m];
                e_dst[g * 2 + head] = eD[head * 2][m] + eD[head * 2 + 1][m];
            }
        }
        __syncthreads();
    }
}

// ---------------- aggregation: 16B/lane gathers, 4 edges per instruction ----
template <int FINAL>
__device__ __forceinline__ void agg_body(const _Float16* __restrict__ Hh,
                                         const float* __restrict__ e_src,
                                         const float* __restrict__ e_dst,
                                         const int* __restrict__ row_ptr,
                                         const int* __restrict__ csr_src,
                                         const float* __restrict__ bias,
                                         float* __restrict__ outf,
                                         unsigned short* __restrict__ ohi,
                                         unsigned short* __restrict__ olo) {
    int lane = threadIdx.x & 63;
    int wv   = threadIdx.x >> 6;
    int d    = blockIdx.x * 4 + wv;
    if (d >= NNODES) return;
    int qt   = lane >> 4;
    int cl   = lane & 15;
    int head = cl >> 3;
    int c0   = cl * 8;
    float ed = e_dst[d * 2 + head];
    int beg = row_ptr[d], end = row_ptr[d + 1];
    float acc[8] = {0.f, 0.f, 0.f, 0.f, 0.f, 0.f, 0.f, 0.f};
    float ssum = 0.f;
    int j = beg;
    for (; j + 16 <= end; j += 16) {
        int s0 = csr_src[j + qt],      s1 = csr_src[j + 4 + qt];
        int s2 = csr_src[j + 8 + qt],  s3 = csr_src[j + 12 + qt];
        h16x8 h0 = *(const h16x8*)(Hh + (size_t)s0 * 128 + c0);
        h16x8 h1 = *(const h16x8*)(Hh + (size_t)s1 * 128 + c0);
        h16x8 h2 = *(const h16x8*)(Hh + (size_t)s2 * 128 + c0);
        h16x8 h3 = *(const h16x8*)(Hh + (size_t)s3 * 128 + c0);
        float t0 = e_src[s0 * 2 + head] + ed, t1 = e_src[s1 * 2 + head] + ed;
        float t2 = e_src[s2 * 2 + head] + ed, t3 = e_src[s3 * 2 + head] + ed;
        t0 = t0 > 0.f ? t0 : NEG_SLOPE * t0;  t1 = t1 > 0.f ? t1 : NEG_SLOPE * t1;
        t2 = t2 > 0.f ? t2 : NEG_SLOPE * t2;  t3 = t3 > 0.f ? t3 : NEG_SLOPE * t3;
        float p0 = __expf(t0), p1 = __expf(t1), p2 = __expf(t2), p3 = __expf(t3);
        #pragma unroll
        for (int c = 0; c < 8; c++)
            acc[c] += p0 * (float)h0[c] + p1 * (float)h1[c]
                    + p2 * (float)h2[c] + p3 * (float)h3[c];
        ssum += p0 + p1 + p2 + p3;
    }
    for (; j < end; j += 4) {
        int idx = j + qt;
        bool valid = idx < end;
        int s = csr_src[valid ? idx : end - 1];
        float t = e_src[s * 2 + head] + ed;
        t = t > 0.f ? t : NEG_SLOPE * t;
        float p = valid ? __expf(t) : 0.f;
        h16x8 hq = *(const h16x8*)(Hh + (size_t)s * 128 + c0);
        #pragma unroll
        for (int c = 0; c < 8; c++) acc[c] += p * (float)hq[c];
        ssum += p;
    }
    #pragma unroll
    for (int c = 0; c < 8; c++) {
        acc[c] += __shfl_xor(acc[c], 16);
        acc[c] += __shfl_xor(acc[c], 32);
    }
    ssum += __shfl_xor(ssum, 16);
    ssum += __shfl_xor(ssum, 32);
    if (qt == 0) {
        float inv = 1.0f / ssum;
        f32x4 b0 = *(const f32x4*)(bias + c0);
        f32x4 b1 = *(const f32x4*)(bias + c0 + 4);
        float o[8];
        #pragma unroll
        for (int c = 0; c < 8; c++) {
            float bv = (c < 4) ? b0[c] : b1[c - 4];
            o[c] = acc[c] * inv + bv;
        }
        if (FINAL) {
            f32x4 w0 = {o[0], o[1], o[2], o[3]};
            f32x4 w1 = {o[4], o[5], o[6], o[7]};
            *(f32x4*)(outf + (size_t)d * 128 + c0)     = w0;
            *(f32x4*)(outf + (size_t)d * 128 + c0 + 4) = w1;
        } else {
            us8 vh, vl;
            #pragma unroll
            for (int c = 0; c < 8; c++) {
                float oc = fmaxf(o[c], 0.f);
                unsigned short hbits = f2bf(oc);
                vh[c] = hbits;
                vl[c] = f2bf(oc - bf2f(hbits));
            }
            *(us8*)&ohi[(size_t)d * 128 + c0] = vh;
            *(us8*)&olo[(size_t)d * 128 + c0] = vl;
        }
    }
}

__global__ __launch_bounds__(256) void k_aggregate_h(const unsigned short* __restrict__ Hh,
                                                     const float* __restrict__ e_src,
                                                     const float* __restrict__ e_dst,
                                                     const int* __restrict__ row_ptr,
                                                     const int* __restrict__ csr_src,
                                                     const float* __restrict__ bias,
                                                     unsigned short* __restrict__ ohi,
                                                     unsigned short* __restrict__ olo) {
    agg_body<0>((const _Float16*)Hh, e_src, e_dst, row_ptr, csr_src, bias,
                nullptr, ohi, olo);
}

__global__ __launch_bounds__(256) void k_aggregate_f(const unsigned short* __restrict__ Hh,
                                                     const float* __restrict__ e_src,
                                                     const float* __restrict__ e_dst,
                                                     const int* __restrict__ row_ptr,
                                                     const int* __restrict__ csr_src,
                                                     const float* __restrict__ bias,
                                                     float* __restrict__ outf) {
    agg_body<1>((const _Float16*)Hh, e_src, e_dst, row_ptr, csr_src, bias,
                outf, nullptr, nullptr);
}

// ---------------- host ----------------

extern "C" void kernel_launch(void* const* d_in, const int* in_sizes, int n_in,
                              void* d_out, int out_size, void* d_ws, size_t ws_size,
                              hipStream_t stream) {
    const float* x  = (const float*)d_in[0];
    const int*   ei = (const int*)d_in[1];   // int32 (harness converts int64)

    char* ws = (char*)d_ws;
    size_t off = 0;
    auto alloc = [&](size_t bytes) {
        void* p = ws + off;
        off = (off + bytes + 255) & ~(size_t)255;
        return p;
    };
    int*            count   = (int*)alloc((size_t)NNODES * 4);
    int*            row_ptr = (int*)alloc((size_t)(NNODES + 1) * 4);
    int*            csr     = (int*)alloc((size_t)(NEDGES + NNODES) * 4);
    int*            pos     = (int*)alloc((size_t)NEDGES * 4);
    int*            bsum    = (int*)alloc((size_t)SCAN_NB * 4);
    int*            boff    = (int*)alloc((size_t)SCAN_NB * 4);
    unsigned short* hh      = (unsigned short*)alloc((size_t)NNODES * 128 * 2);  // fp16 h
    unsigned short* wthi    = (unsigned short*)alloc((size_t)4 * 16384 * 2);
    unsigned short* wtlo    = (unsigned short*)alloc((size_t)4 * 16384 * 2);
    float*          es      = (float*)alloc((size_t)NNODES * 2 * 4);
    float*          edv     = (float*)alloc((size_t)NNODES * 2 * 4);
    (void)ws_size; (void)in_sizes; (void)n_in; (void)out_size;

    unsigned short* hi = (unsigned short*)d_out;     // act bf16 hi plane
    unsigned short* lo = hi + (size_t)NNODES * 128;  // act bf16 lo plane

    const float* W0   = (const float*)d_in[2];
    const float* W_h  = (const float*)d_in[6];
    const float* Wout = (const float*)d_in[10];

    const float* ash = (const float*)d_in[7];
    const float* adh = (const float*)d_in[8];
    const float* bh  = (const float*)d_in[9];

    struct Layer { const float *as, *ad, *b; };
    Layer L[4] = {
        { (const float*)d_in[3],  (const float*)d_in[4],  (const float*)d_in[5]  },
        { ash,        adh,        bh        },
        { ash + 128,  adh + 128,  bh + 128  },
        { (const float*)d_in[11], (const float*)d_in[12], (const float*)d_in[13] },
    };

    hipMemsetAsync(count, 0, (size_t)NNODES * 4, stream);
    k_wprep<<<256, 256, 0, stream>>>(W0, W_h, Wout, wthi, wtlo);

    const int agg_blocks = (NNODES + 3) / 4;
    for (int l = 0; l < 4; l++) {
        // layer 0: +COUNT_BLOCKS fused count blocks (overlap atomic wall w/ GEMM)
        int grid = (l == 0) ? GEMM_BLOCKS + COUNT_BLOCKS : GEMM_BLOCKS;
        k_gemm_mfma<<<grid, 256, 0, stream>>>(
            x, hi, lo, wthi + (size_t)l * 16384, wtlo + (size_t)l * 16384,
            L[l].as, L[l].ad, hh, es, edv, l == 0 ? 1 : 0, ei, count, pos);
        if (l == 0) {
            // CSR finalize (needs count from the fused dispatch)
            k_bsum   <<<SCAN_NB, 256, 0, stream>>>(count, bsum);
            k_bscan  <<<1, 256, 0, stream>>>(bsum, boff, row_ptr);
            k_rowptr <<<SCAN_NB, 256, 0, stream>>>(count, boff, row_ptr, csr);
            k_scatter<<<(NEDGES + 4 * 256 - 1) / (4 * 256), 256, 0, stream>>>(ei, row_ptr, pos, csr);
        }
        if (l < 3) {
            k_aggregate_h<<<agg_blocks, 256, 0, stream>>>(hh, es, edv, row_ptr, csr,
                                                          L[l].b, hi, lo);
        } else {
            k_aggregate_f<<<agg_blocks, 256, 0, stream>>>(hh, es, edv, row_ptr, csr,
                                                          L[l].b, (float*)d_out);
        }
    }
}

// Round 14
// 511.938 us; speedup vs baseline: 1.0864x; 1.0591x over previous
//
#include <hip/hip_runtime.h>

#define NNODES 50000
#define NEDGES 1600000
#define NEG_SLOPE 0.2f

#define SCAN_NB 256
#define SCAN_CH 196   // ceil(50000/256)

#define MT_ROWS 64
#define NMT 782       // ceil(50000/64)
#define GEMM_BLOCKS 768
#define COUNT_BLOCKS 256

#define SCAT_GROUPS 512
#define SLICE ((NEDGES + SCAT_GROUPS - 1) / SCAT_GROUPS)   // 3125
#define DPART (NNODES / 8)                                  // 6250 exact

// count[] padded: one node per 64B line (stride 16 dwords) — spreads the
// per-line atomic serialization 512 -> 32 atomics/line.
#define CPAD 4   // d << 4

typedef __attribute__((ext_vector_type(8))) short short8;
typedef __attribute__((ext_vector_type(4))) float f32x4;
typedef __attribute__((ext_vector_type(8))) _Float16 h16x8;
typedef __attribute__((ext_vector_type(8))) unsigned short us8;

static __device__ __forceinline__ unsigned short f2bf(float f) {
    unsigned u = __float_as_uint(f);
    unsigned r = u + 0x7FFFu + ((u >> 16) & 1u);   // RNE
    return (unsigned short)(r >> 16);
}
static __device__ __forceinline__ float bf2f(unsigned short h) {
    return __uint_as_float(((unsigned)h) << 16);
}
static __device__ __forceinline__ unsigned short f2h(float f) {
    union { _Float16 x; unsigned short u; } c;
    c.x = (_Float16)f;
    return c.u;
}

// ---------------- CSR build (edge_index arrives as int32) ----------------
// k_count is FUSED into the layer-0 GEMM dispatch — see k_gemm_mfma.

__global__ __launch_bounds__(256) void k_bsum(const int* __restrict__ count,
                                              int* __restrict__ bsum) {
    __shared__ int red[4];
    int t = threadIdx.x, b = blockIdx.x;
    int idx = b * SCAN_CH + t;
    int v = (t < SCAN_CH && idx < NNODES) ? count[idx << CPAD] + 1 : 0;  // +1 self loop
    #pragma unroll
    for (int m = 1; m <= 32; m <<= 1) v += __shfl_xor(v, m);
    if ((t & 63) == 0) red[t >> 6] = v;
    __syncthreads();
    if (t == 0) bsum[b] = red[0] + red[1] + red[2] + red[3];
}

__global__ __launch_bounds__(256) void k_bscan(const int* __restrict__ bsum,
                                               int* __restrict__ boff,
                                               int* __restrict__ row_ptr) {
    __shared__ int s[256];
    int t = threadIdx.x;
    int v = bsum[t];
    s[t] = v;
    __syncthreads();
    for (int off = 1; off < 256; off <<= 1) {
        int u = (t >= off) ? s[t - off] : 0;
        __syncthreads();
        s[t] += u;
        __syncthreads();
    }
    boff[t] = s[t] - v;
    if (t == 255) row_ptr[NNODES] = s[255];
}

__global__ __launch_bounds__(256) void k_rowptr(const int* __restrict__ count,
                                                const int* __restrict__ boff,
                                                int* __restrict__ row_ptr,
                                                int* __restrict__ csr_src) {
    __shared__ int s[256];
    int t = threadIdx.x, b = blockIdx.x;
    int idx = b * SCAN_CH + t;
    bool valid = (t < SCAN_CH && idx < NNODES);
    int v = valid ? count[idx << CPAD] + 1 : 0;
    s[t] = v;
    __syncthreads();
    for (int off = 1; off < 256; off <<= 1) {
        int u = (t >= off) ? s[t - off] : 0;
        __syncthreads();
        s[t] += u;
        __syncthreads();
    }
    if (valid) {
        int run = boff[b] + s[t] - v;
        row_ptr[idx] = run;
        csr_src[run] = idx;                  // self-loop slot 0
    }
}

// XCD-partitioned scatter: blocks in groups of 8 share edge-slice grp,
// residue part = blockIdx&7 writes only d in [part*DPART, (part+1)*DPART).
// Exactly-once by d-partition (correct regardless of block->XCD mapping);
// if blockIdx%8 ~ XCD, csr lines accumulate in ONE L2 -> writes merge.
__global__ __launch_bounds__(256) void k_scatter(const int* __restrict__ ei,
                                                 const int* __restrict__ row_ptr,
                                                 const int* __restrict__ pos,
                                                 int* __restrict__ csr_src) {
    int grp  = blockIdx.x >> 3;
    int part = blockIdx.x & 7;
    int lo = grp * SLICE;
    int hi = lo + SLICE; if (hi > NEDGES) hi = NEDGES;
    int dlo = part * DPART;
    int dhi = dlo + DPART;
    for (int e = lo + threadIdx.x; e < hi; e += 256) {
        int d = ei[NEDGES + e];
        if (d >= dlo && d < dhi) {
            int s = ei[e];
            csr_src[row_ptr[d] + 1 + pos[e]] = s;
        }
    }
}

// ---------------- W prep: fp32 [k][n] -> transposed bf16 hi/lo [n][k] -------
__global__ __launch_bounds__(256) void k_wprep(const float* __restrict__ W0,
                                               const float* __restrict__ Wh,
                                               const float* __restrict__ Wout,
                                               unsigned short* __restrict__ wthi,
                                               unsigned short* __restrict__ wtlo) {
    int t = blockIdx.x * blockDim.x + threadIdx.x;   // 0..65535
    int l = t >> 14;
    int i = t & 16383;       // k*128+n
    int k = i >> 7, n = i & 127;
    const float* src = (l == 0) ? W0 : (l == 3) ? Wout : (Wh + (size_t)(l - 1) * 16384);
    float v = src[i];
    unsigned short h = f2bf(v);
    wthi[(size_t)l * 16384 + n * 128 + k] = h;
    wtlo[(size_t)l * 16384 + n * 128 + k] = f2bf(v - bf2f(h));
}

// ---------------- MFMA GEMM + attention epilogue (+ fused edge-count) -------
// C = X*W via split-bf16: Xh*Wh + Xh*Wl + Xl*Wh (err ~2^-17 rel).
// Blocks >= GEMM_BLOCKS run the CSR count pass (layer 0 only) with the
// line-padded count array.
__global__ __launch_bounds__(256, 3) void k_gemm_mfma(
        const float* __restrict__ X,
        const unsigned short* __restrict__ Ahi, const unsigned short* __restrict__ Alo,
        const unsigned short* __restrict__ Wthi, const unsigned short* __restrict__ Wtlo,
        const float* __restrict__ a_src, const float* __restrict__ a_dst,
        unsigned short* __restrict__ Hh,
        float* __restrict__ e_src, float* __restrict__ e_dst, int use_x,
        const int* __restrict__ ei, int* __restrict__ count, int* __restrict__ pos)
{
    __shared__ __align__(16) short sAhi[MT_ROWS * 128];   // 16 KB
    __shared__ __align__(16) short sAlo[MT_ROWS * 128];   // 16 KB
    __shared__ float eS[4][MT_ROWS];
    __shared__ float eD[4][MT_ROWS];

    if (blockIdx.x >= GEMM_BLOCKS) {
        // ---- fused CSR count path (padded count: d<<CPAD) ----
        int t = (blockIdx.x - GEMM_BLOCKS) * 256 + threadIdx.x;   // 0..65535
        for (int base = t; base < NEDGES; base += 8 * 65536) {
            #pragma unroll
            for (int i = 0; i < 8; i++) {
                int e = base + i * 65536;
                if (e < NEDGES) pos[e] = atomicAdd(&count[ei[NEDGES + e] << CPAD], 1);
            }
        }
        return;
    }

    const int tid  = threadIdx.x;
    const int lane = tid & 63;
    const int w    = tid >> 6;
    const int l15  = lane & 15;
    const int quad = lane >> 4;

    short8 Bh[2][4], Bl[2][4];
    #pragma unroll
    for (int nt = 0; nt < 2; nt++) {
        int n = w * 32 + nt * 16 + l15;
        #pragma unroll
        for (int ks = 0; ks < 4; ks++) {
            Bh[nt][ks] = *(const short8*)(Wthi + (size_t)n * 128 + ks * 32 + quad * 8);
            Bl[nt][ks] = *(const short8*)(Wtlo + (size_t)n * 128 + ks * 32 + quad * 8);
        }
    }
    float as0 = a_src[w * 32 + l15],      ad0 = a_dst[w * 32 + l15];
    float as1 = a_src[w * 32 + 16 + l15], ad1 = a_dst[w * 32 + 16 + l15];

    for (int mt0 = blockIdx.x; mt0 < NMT; mt0 += GEMM_BLOCKS) {
        const int row0 = mt0 * MT_ROWS;

        for (int i = tid; i < MT_ROWS * 16; i += 256) {
            int m  = i >> 4;
            int kc = i & 15;
            int g  = row0 + m; if (g > NNODES - 1) g = NNODES - 1;
            int cp = kc ^ (m & 15);
            short8 vh, vl;
            if (use_x) {
                float4 xa = *(const float4*)(X + (size_t)g * 128 + kc * 8);
                float4 xb = *(const float4*)(X + (size_t)g * 128 + kc * 8 + 4);
                float xs[8] = {xa.x, xa.y, xa.z, xa.w, xb.x, xb.y, xb.z, xb.w};
                #pragma unroll
                for (int q = 0; q < 8; q++) {
                    unsigned short h = f2bf(xs[q]);
                    vh[q] = (short)h;
                    vl[q] = (short)f2bf(xs[q] - bf2f(h));
                }
            } else {
                vh = *(const short8*)(Ahi + (size_t)g * 128 + kc * 8);
                vl = *(const short8*)(Alo + (size_t)g * 128 + kc * 8);
            }
            *(short8*)&sAhi[m * 128 + cp * 8] = vh;
            *(short8*)&sAlo[m * 128 + cp * 8] = vl;
        }
        __syncthreads();

        f32x4 zero = {0.f, 0.f, 0.f, 0.f};
        f32x4 acc[4][2];
        #pragma unroll
        for (int mt = 0; mt < 4; mt++) { acc[mt][0] = zero; acc[mt][1] = zero; }
        #pragma unroll
        for (int mt = 0; mt < 4; mt++) {
            int m = mt * 16 + l15;
            #pragma unroll
            for (int ks = 0; ks < 4; ks++) {
                int kc = ks * 4 + quad;
                int cp = kc ^ l15;
                short8 ah = *(const short8*)&sAhi[m * 128 + cp * 8];
                short8 al = *(const short8*)&sAlo[m * 128 + cp * 8];
                #pragma unroll
                for (int nt = 0; nt < 2; nt++) {
                    acc[mt][nt] = __builtin_amdgcn_mfma_f32_16x16x32_bf16(ah, Bh[nt][ks], acc[mt][nt], 0, 0, 0);
                    acc[mt][nt] = __builtin_amdgcn_mfma_f32_16x16x32_bf16(al, Bh[nt][ks], acc[mt][nt], 0, 0, 0);
                    acc[mt][nt] = __builtin_amdgcn_mfma_f32_16x16x32_bf16(ah, Bl[nt][ks], acc[mt][nt], 0, 0, 0);
                }
            }
        }

        #pragma unroll
        for (int mt = 0; mt < 4; mt++) {
            #pragma unroll
            for (int r = 0; r < 4; r++) {
                int m = mt * 16 + quad * 4 + r;
                int g = row0 + m;
                float v0 = acc[mt][0][r], v1 = acc[mt][1][r];
                if (g < NNODES) {
                    int n0 = w * 32 + l15;
                    Hh[(size_t)g * 128 + n0]      = f2h(v0);
                    Hh[(size_t)g * 128 + n0 + 16] = f2h(v1);
                }
                float ps = v0 * as0 + v1 * as1;
                float pd = v0 * ad0 + v1 * ad1;
                ps += __shfl_xor(ps, 1); ps += __shfl_xor(ps, 2);
                ps += __shfl_xor(ps, 4); ps += __shfl_xor(ps, 8);
                pd += __shfl_xor(pd, 1); pd += __shfl_xor(pd, 2);
                pd += __shfl_xor(pd, 4); pd += __shfl_xor(pd, 8);
                if (l15 == 0) { eS[w][m] = ps; eD[w][m] = pd; }
            }
        }
        __syncthreads();
        if (tid < MT_ROWS * 2) {
            int m = tid >> 1, head = tid & 1;
            int g = row0 + m;
            if (g < NNODES) {
                e_src[g * 2 + head] = eS[head * 2][m] + eS[head * 2 + 1][m];
                e_dst[g * 2 + head] = eD[head * 2][m] + eD[head * 2 + 1][m];
            }
        }
        __syncthreads();
    }
}

// ---------------- aggregation: 16B/lane gathers, 4 edges per instruction ----
template <int FINAL>
__device__ __forceinline__ void agg_body(const _Float16* __restrict__ Hh,
                                         const float* __restrict__ e_src,
                                         const float* __restrict__ e_dst,
                                         const int* __restrict__ row_ptr,
                                         const int* __restrict__ csr_src,
                                         const float* __restrict__ bias,
                                         float* __restrict__ outf,
                                         unsigned short* __restrict__ ohi,
                                         unsigned short* __restrict__ olo) {
    int lane = threadIdx.x & 63;
    int wv   = threadIdx.x >> 6;
    int d    = blockIdx.x * 4 + wv;
    if (d >= NNODES) return;
    int qt   = lane >> 4;
    int cl   = lane & 15;
    int head = cl >> 3;
    int c0   = cl * 8;
    float ed = e_dst[d * 2 + head];
    int beg = row_ptr[d], end = row_ptr[d + 1];
    float acc[8] = {0.f, 0.f, 0.f, 0.f, 0.f, 0.f, 0.f, 0.f};
    float ssum = 0.f;
    int j = beg;
    for (; j + 16 <= end; j += 16) {
        int s0 = csr_src[j + qt],      s1 = csr_src[j + 4 + qt];
        int s2 = csr_src[j + 8 + qt],  s3 = csr_src[j + 12 + qt];
        h16x8 h0 = *(const h16x8*)(Hh + (size_t)s0 * 128 + c0);
        h16x8 h1 = *(const h16x8*)(Hh + (size_t)s1 * 128 + c0);
        h16x8 h2 = *(const h16x8*)(Hh + (size_t)s2 * 128 + c0);
        h16x8 h3 = *(const h16x8*)(Hh + (size_t)s3 * 128 + c0);
        float t0 = e_src[s0 * 2 + head] + ed, t1 = e_src[s1 * 2 + head] + ed;
        float t2 = e_src[s2 * 2 + head] + ed, t3 = e_src[s3 * 2 + head] + ed;
        t0 = t0 > 0.f ? t0 : NEG_SLOPE * t0;  t1 = t1 > 0.f ? t1 : NEG_SLOPE * t1;
        t2 = t2 > 0.f ? t2 : NEG_SLOPE * t2;  t3 = t3 > 0.f ? t3 : NEG_SLOPE * t3;
        float p0 = __expf(t0), p1 = __expf(t1), p2 = __expf(t2), p3 = __expf(t3);
        #pragma unroll
        for (int c = 0; c < 8; c++)
            acc[c] += p0 * (float)h0[c] + p1 * (float)h1[c]
                    + p2 * (float)h2[c] + p3 * (float)h3[c];
        ssum += p0 + p1 + p2 + p3;
    }
    for (; j < end; j += 4) {
        int idx = j + qt;
        bool valid = idx < end;
        int s = csr_src[valid ? idx : end - 1];
        float t = e_src[s * 2 + head] + ed;
        t = t > 0.f ? t : NEG_SLOPE * t;
        float p = valid ? __expf(t) : 0.f;
        h16x8 hq = *(const h16x8*)(Hh + (size_t)s * 128 + c0);
        #pragma unroll
        for (int c = 0; c < 8; c++) acc[c] += p * (float)hq[c];
        ssum += p;
    }
    #pragma unroll
    for (int c = 0; c < 8; c++) {
        acc[c] += __shfl_xor(acc[c], 16);
        acc[c] += __shfl_xor(acc[c], 32);
    }
    ssum += __shfl_xor(ssum, 16);
    ssum += __shfl_xor(ssum, 32);
    if (qt == 0) {
        float inv = 1.0f / ssum;
        f32x4 b0 = *(const f32x4*)(bias + c0);
        f32x4 b1 = *(const f32x4*)(bias + c0 + 4);
        float o[8];
        #pragma unroll
        for (int c = 0; c < 8; c++) {
            float bv = (c < 4) ? b0[c] : b1[c - 4];
            o[c] = acc[c] * inv + bv;
        }
        if (FINAL) {
            f32x4 w0 = {o[0], o[1], o[2], o[3]};
            f32x4 w1 = {o[4], o[5], o[6], o[7]};
            *(f32x4*)(outf + (size_t)d * 128 + c0)     = w0;
            *(f32x4*)(outf + (size_t)d * 128 + c0 + 4) = w1;
        } else {
            us8 vh, vl;
            #pragma unroll
            for (int c = 0; c < 8; c++) {
                float oc = fmaxf(o[c], 0.f);
                unsigned short hbits = f2bf(oc);
                vh[c] = hbits;
                vl[c] = f2bf(oc - bf2f(hbits));
            }
            *(us8*)&ohi[(size_t)d * 128 + c0] = vh;
            *(us8*)&olo[(size_t)d * 128 + c0] = vl;
        }
    }
}

__global__ __launch_bounds__(256) void k_aggregate_h(const unsigned short* __restrict__ Hh,
                                                     const float* __restrict__ e_src,
                                                     const float* __restrict__ e_dst,
                                                     const int* __restrict__ row_ptr,
                                                     const int* __restrict__ csr_src,
                                                     const float* __restrict__ bias,
                                                     unsigned short* __restrict__ ohi,
                                                     unsigned short* __restrict__ olo) {
    agg_body<0>((const _Float16*)Hh, e_src, e_dst, row_ptr, csr_src, bias,
                nullptr, ohi, olo);
}

__global__ __launch_bounds__(256) void k_aggregate_f(const unsigned short* __restrict__ Hh,
                                                     const float* __restrict__ e_src,
                                                     const float* __restrict__ e_dst,
                                                     const int* __restrict__ row_ptr,
                                                     const int* __restrict__ csr_src,
                                                     const float* __restrict__ bias,
                                                     float* __restrict__ outf) {
    agg_body<1>((const _Float16*)Hh, e_src, e_dst, row_ptr, csr_src, bias,
                outf, nullptr, nullptr);
}

// ---------------- host ----------------

extern "C" void kernel_launch(void* const* d_in, const int* in_sizes, int n_in,
                              void* d_out, int out_size, void* d_ws, size_t ws_size,
                              hipStream_t stream) {
    const float* x  = (const float*)d_in[0];
    const int*   ei = (const int*)d_in[1];   // int32 (harness converts int64)

    char* ws = (char*)d_ws;
    size_t off = 0;
    auto alloc = [&](size_t bytes) {
        void* p = ws + off;
        off = (off + bytes + 255) & ~(size_t)255;
        return p;
    };
    int*            count   = (int*)alloc((size_t)NNODES * 64);      // padded: 64B/node
    int*            row_ptr = (int*)alloc((size_t)(NNODES + 1) * 4);
    int*            csr     = (int*)alloc((size_t)(NEDGES + NNODES) * 4);
    int*            pos     = (int*)alloc((size_t)NEDGES * 4);
    int*            bsum    = (int*)alloc((size_t)SCAN_NB * 4);
    int*            boff    = (int*)alloc((size_t)SCAN_NB * 4);
    unsigned short* hh      = (unsigned short*)alloc((size_t)NNODES * 128 * 2);  // fp16 h
    unsigned short* wthi    = (unsigned short*)alloc((size_t)4 * 16384 * 2);
    unsigned short* wtlo    = (unsigned short*)alloc((size_t)4 * 16384 * 2);
    float*          es      = (float*)alloc((size_t)NNODES * 2 * 4);
    float*          edv     = (float*)alloc((size_t)NNODES * 2 * 4);
    (void)ws_size; (void)in_sizes; (void)n_in; (void)out_size;

    unsigned short* hi = (unsigned short*)d_out;     // act bf16 hi plane
    unsigned short* lo = hi + (size_t)NNODES * 128;  // act bf16 lo plane

    const float* W0   = (const float*)d_in[2];
    const float* W_h  = (const float*)d_in[6];
    const float* Wout = (const float*)d_in[10];

    const float* ash = (const float*)d_in[7];
    const float* adh = (const float*)d_in[8];
    const float* bh  = (const float*)d_in[9];

    struct Layer { const float *as, *ad, *b; };
    Layer L[4] = {
        { (const float*)d_in[3],  (const float*)d_in[4],  (const float*)d_in[5]  },
        { ash,        adh,        bh        },
        { ash + 128,  adh + 128,  bh + 128  },
        { (const float*)d_in[11], (const float*)d_in[12], (const float*)d_in[13] },
    };

    hipMemsetAsync(count, 0, (size_t)NNODES * 64, stream);
    k_wprep<<<256, 256, 0, stream>>>(W0, W_h, Wout, wthi, wtlo);

    const int agg_blocks = (NNODES + 3) / 4;
    for (int l = 0; l < 4; l++) {
        // layer 0: +COUNT_BLOCKS fused count blocks (overlap atomic wall w/ GEMM)
        int grid = (l == 0) ? GEMM_BLOCKS + COUNT_BLOCKS : GEMM_BLOCKS;
        k_gemm_mfma<<<grid, 256, 0, stream>>>(
            x, hi, lo, wthi + (size_t)l * 16384, wtlo + (size_t)l * 16384,
            L[l].as, L[l].ad, hh, es, edv, l == 0 ? 1 : 0, ei, count, pos);
        if (l == 0) {
            // CSR finalize (needs count from the fused dispatch)
            k_bsum   <<<SCAN_NB, 256, 0, stream>>>(count, bsum);
            k_bscan  <<<1, 256, 0, stream>>>(bsum, boff, row_ptr);
            k_rowptr <<<SCAN_NB, 256, 0, stream>>>(count, boff, row_ptr, csr);
            k_scatter<<<SCAT_GROUPS * 8, 256, 0, stream>>>(ei, row_ptr, pos, csr);
        }
        if (l < 3) {
            k_aggregate_h<<<agg_blocks, 256, 0, stream>>>(hh, es, edv, row_ptr, csr,
                                                          L[l].b, hi, lo);
        } else {
            k_aggregate_f<<<agg_blocks, 256, 0, stream>>>(hh, es, edv, row_ptr, csr,
                                                          L[l].b, (float*)d_out);
        }
    }
}